// Round 11
// baseline (222.028 us; speedup 1.0000x reference)
//
#include <hip/hip_runtime.h>
#include <cstdint>
#include <cstddef>

#define IN_F 128
#define HID  128
#define OUTF 64

typedef unsigned int   uint32;
typedef unsigned short ushort16;

using frag_ab = __attribute__((ext_vector_type(8))) short;   // 8 bf16
using frag_cd = __attribute__((ext_vector_type(4))) float;   // 4 f32

static constexpr int TPB = 256;
static constexpr int PT_TILE = 2048;   // edges per partition block
static constexpr int PT_EPT  = 8;      // edges per thread
static constexpr int MAXBK   = 512;    // max buckets (N <= 131072) for bucketed path
static constexpr int PART_SMEM = 19456; // partition LDS only (gemm body is LDS-free now)

// ---------- bf16 helpers (RNE) ----------
__device__ __forceinline__ float bflo(uint32 u) { return __uint_as_float(u << 16); }
__device__ __forceinline__ float bfhi(uint32 u) { return __uint_as_float(u & 0xFFFF0000u); }
__device__ __forceinline__ ushort16 f2bf(float f) {
    uint32 x = __float_as_uint(f);
    x = (x + 0x7FFFu + ((x >> 16) & 1u)) >> 16;
    return (ushort16)x;
}
__device__ __forceinline__ uint32 packbf(float a, float b) {
    return (uint32)f2bf(a) | ((uint32)f2bf(b) << 16);
}

__device__ __forceinline__ int load_idx(const void* p, int i, bool i64) {
    return i64 ? (int)((const long long*)p)[i] : ((const int*)p)[i];
}

// ---------- prep: detect idx dtype + zero bcur + transpose W1/W2 to bf16 [c][k] ----------
// block 0: detect + bcur zero; blocks 1..: weight transpose (24576 elems)
__global__ void prep_kernel(const uint32* __restrict__ p, int* __restrict__ flag,
                            int* __restrict__ bcur,
                            const float* __restrict__ W1, const float* __restrict__ W2,
                            ushort16* __restrict__ W1t, ushort16* __restrict__ W2t)
{
    int tid = threadIdx.x;
    if (blockIdx.x == 0) {
        __shared__ int anynz;
        if (tid == 0) anynz = 0;
        __syncthreads();
        if (p[2 * tid + 1] != 0u) atomicOr(&anynz, 1);
        bcur[tid] = 0; bcur[tid + 256] = 0;
        __syncthreads();
        if (tid == 0) *flag = (anynz == 0) ? 1 : 0;
        return;
    }
    int i = (blockIdx.x - 1) * TPB + tid;
    if (i < 128 * 128) {
        int k = i >> 7, c = i & 127;
        W1t[c * 128 + k] = f2bf(W1[i]);
    } else {
        int j = i - 128 * 128;
        if (j < 128 * 64) {
            int k = j >> 6, c = j & 63;
            W2t[c * 128 + k] = f2bf(W2[j]);
        }
    }
}

// ---------- LDS-free MFMA GEMM body: out[r][:] = bf16((X@W)[r] * (SCALE? dis[r]:1)) ----------
// Wt is bf16 [col][k=128] in GLOBAL memory — same addresses across blocks -> L2 broadcast.
template <int C, bool XBF, bool SCALE>
__device__ __forceinline__ void gemm_global_body(
    int gb, const void* __restrict__ Xv, const ushort16* __restrict__ Wt,
    const float* __restrict__ dis, ushort16* __restrict__ out, int M)
{
    constexpr int NB = C / 16;
    int wid  = threadIdx.x >> 6;
    int lane = threadIdx.x & 63;
    int g    = lane >> 4;
    int li   = lane & 15;

    int row = gb * 64 + wid * 16 + li;
    int rc  = min(row, M - 1);

    frag_cd acc[NB];
#pragma unroll
    for (int i = 0; i < NB; ++i) acc[i] = (frag_cd)0.0f;

#pragma unroll
    for (int t = 0; t < 4; ++t) {
        frag_ab a;
        if (XBF) {
            const ushort16* xp = (const ushort16*)Xv + (size_t)rc * 128 + t * 32 + g * 8;
            a = *(const frag_ab*)xp;
        } else {
            const float* xp = (const float*)Xv + (size_t)rc * 128 + t * 32 + g * 8;
            float4 pp = *(const float4*)xp;
            float4 qq = *(const float4*)(xp + 4);
            a[0] = (short)f2bf(pp.x); a[1] = (short)f2bf(pp.y);
            a[2] = (short)f2bf(pp.z); a[3] = (short)f2bf(pp.w);
            a[4] = (short)f2bf(qq.x); a[5] = (short)f2bf(qq.y);
            a[6] = (short)f2bf(qq.z); a[7] = (short)f2bf(qq.w);
        }
#pragma unroll
        for (int cb = 0; cb < NB; ++cb) {
            frag_ab b = *(const frag_ab*)&Wt[(size_t)(cb * 16 + li) * 128 + t * 32 + g * 8];
            acc[cb] = __builtin_amdgcn_mfma_f32_16x16x32_bf16(a, b, acc[cb], 0, 0, 0);
        }
    }

    int ro = gb * 64 + wid * 16 + g * 4;
#pragma unroll
    for (int r = 0; r < 4; ++r) {
        int rr = ro + r;
        if (rr < M) {
            float dsc = SCALE ? dis[rr] : 1.0f;
#pragma unroll
            for (int cb = 0; cb < NB; ++cb)
                out[(size_t)rr * C + cb * 16 + li] = f2bf(acc[cb][r] * dsc);
        }
    }
}

template <int C, bool XBF, bool SCALE>
__global__ __launch_bounds__(256) void gemm_global_kernel(
    const void* __restrict__ Xv, const ushort16* __restrict__ Wt,
    const float* __restrict__ dis, ushort16* __restrict__ out, int M)
{
    gemm_global_body<C, XBF, SCALE>(blockIdx.x, Xv, Wt, dis, out, M);
}

// ---------- partition body (19.5 KB LDS) ----------
__device__ void partition_body(char* smem, const void* __restrict__ ei, int E, bool i64,
                               int nbuckets, int bcap,
                               int* __restrict__ bcur, uint32* __restrict__ bbuf)
{
    uint32*   stash  = (uint32*)smem;                 // 8192 B
    ushort16* bidx   = (ushort16*)(smem + 8192);      // 4096 B
    int*      hist   = (int*)(smem + 12288);          // 2048 B
    int*      scanb  = (int*)(smem + 14336);          // 2048 B
    int*      gbase  = (int*)(smem + 16384);          // 2048 B
    int*      sum256 = (int*)(smem + 18432);          // 1024 B

    int tile0 = blockIdx.x * PT_TILE;
    int tid = threadIdx.x;

    for (int i = tid; i < nbuckets; i += 256) hist[i] = 0;
    __syncthreads();

    uint32 pck[PT_EPT];
    int    lofs[PT_EPT];
    short  bkt[PT_EPT];
#pragma unroll
    for (int j = 0; j < PT_EPT; ++j) {
        int e = tile0 + j * 256 + tid;
        if (e < E) {
            int s = load_idx(ei, e, i64);
            int d = load_idx(ei, E + e, i64);
            int b = d >> 8;
            pck[j]  = (uint32)s | ((uint32)(d & 255) << 24);
            bkt[j]  = (short)b;
            lofs[j] = atomicAdd(&hist[b], 1);
        } else bkt[j] = -1;
    }
    __syncthreads();

    for (int i = tid; i < nbuckets; i += 256)
        gbase[i] = hist[i] ? atomicAdd(&bcur[i], hist[i]) : 0;

    {   // exclusive scan of hist (2 elems/thread, MAXBK=512)
        int lt = tid * 2;
        int h0 = 0, h1 = 0;
        if (lt + 0 < nbuckets) h0 = hist[lt + 0];
        if (lt + 1 < nbuckets) h1 = hist[lt + 1];
        int lsum = h0 + h1;
        sum256[tid] = lsum;
        __syncthreads();
        for (int off = 1; off < 256; off <<= 1) {
            int t = (tid >= off) ? sum256[tid - off] : 0;
            __syncthreads();
            sum256[tid] += t;
            __syncthreads();
        }
        int excl = sum256[tid] - lsum;
        if (lt + 0 < nbuckets) scanb[lt + 0] = excl;
        if (lt + 1 < nbuckets) scanb[lt + 1] = excl + h0;
    }
    __syncthreads();

#pragma unroll
    for (int j = 0; j < PT_EPT; ++j) {
        if (bkt[j] >= 0) {
            int p = scanb[bkt[j]] + lofs[j];
            stash[p] = pck[j];
            bidx[p]  = (ushort16)bkt[j];
        }
    }
    __syncthreads();

    int total = min(PT_TILE, E - tile0);
    for (int k = tid; k < total; k += 256) {
        int b = bidx[k];
        int dst = gbase[b] + (k - scanb[b]);
        if (dst < bcap) bbuf[(size_t)b * bcap + dst] = stash[k];
    }
}

// ---------- mega1: blocks [0,PB) partition ; blocks [PB,..) raw layer-1 GEMM (LDS-free) ----------
__global__ __launch_bounds__(256) void mega1_kernel(
    const void* __restrict__ ei, int E, const int* __restrict__ flag,
    int nbuckets, int bcap, int* __restrict__ bcur, uint32* __restrict__ bbuf,
    const float* __restrict__ X, const ushort16* __restrict__ W1t,
    ushort16* __restrict__ H, int M, int PB)
{
    __shared__ char smem[PART_SMEM];
    if ((int)blockIdx.x < PB) {
        partition_body(smem, ei, E, (*flag != 0), nbuckets, bcap, bcur, bbuf);
    } else {
        gemm_global_body<HID, false, false>(blockIdx.x - PB, X, W1t, nullptr, H, M);
    }
}

// ---------- bucket_build: bbase scan + degree/dis/row_ptr + CSR fill, one kernel ----------
__global__ __launch_bounds__(256) void bucket_build_kernel(
    const uint32* __restrict__ bbuf, const int* __restrict__ bcur,
    int* __restrict__ counts, float* __restrict__ dis, int* __restrict__ row_ptr,
    int* __restrict__ csr, int N, int nbuckets, int bcap)
{
    __shared__ int pcnt[512];
    __shared__ int pinc[256];
    __shared__ int h[256];
    __shared__ int sc[256];
    __shared__ int cur[256];

    int tid = threadIdx.x;
    int b = blockIdx.x;

    // --- bbase: redundant per-block exclusive scan over bucket totals
    pcnt[tid]       = (tid < nbuckets)       ? min(bcur[tid], bcap)       : 0;
    pcnt[tid + 256] = (tid + 256 < nbuckets) ? min(bcur[tid + 256], bcap) : 0;
    h[tid] = 0;
    __syncthreads();
    int ps = pcnt[2 * tid] + pcnt[2 * tid + 1];
    pinc[tid] = ps;
    __syncthreads();
    for (int off = 1; off < 256; off <<= 1) {
        int t = (tid >= off) ? pinc[tid - off] : 0;
        __syncthreads();
        pinc[tid] += t;
        __syncthreads();
    }
    int p2 = b >> 1;
    int bbase = pinc[p2] - (pcnt[2 * p2] + pcnt[2 * p2 + 1]) + ((b & 1) ? pcnt[b - 1] : 0);

    // --- degree histogram over this bucket's packed entries
    int cnt = min(bcur[b], bcap);
    const uint32* src = bbuf + (size_t)b * bcap;
    for (int k = tid; k < cnt; k += 256) atomicAdd(&h[src[k] >> 24], 1);
    __syncthreads();

    // --- local exclusive scan of per-node counts
    int v = h[tid];
    sc[tid] = v;
    __syncthreads();
    for (int off = 1; off < 256; off <<= 1) {
        int t = (tid >= off) ? sc[tid - off] : 0;
        __syncthreads();
        sc[tid] += t;
        __syncthreads();
    }
    int myrow = bbase + sc[tid] - v;
    int node = (b << 8) + tid;
    if (node < N) {
        counts[node]  = v;
        dis[node]     = rsqrtf((float)(v + 1));   // +1 self-loop
        row_ptr[node] = myrow;
    }
    cur[tid] = myrow;
    __syncthreads();

    // --- CSR fill (bbuf chunk is L2-hot from the histogram pass)
    for (int k = tid; k < cnt; k += 256) {
        uint32 p = src[k];
        int dl = p >> 24;
        int pos = atomicAdd(&cur[dl], 1);
        csr[pos] = (int)(p & 0xFFFFFF);
    }
}

// ---------- legacy build path (N too large for bucketed path) ----------
__global__ void hist_kernel(const void* __restrict__ ei, int E, const int* __restrict__ flag,
                            int* __restrict__ counts) {
    int e = blockIdx.x * TPB + threadIdx.x;
    if (e >= E) return;
    bool i64 = (*flag != 0);
    atomicAdd(&counts[load_idx(ei, E + e, i64)], 1);
}

__global__ void fill_kernel(const void* __restrict__ ei, int E, const int* __restrict__ flag,
                            int* __restrict__ cursor, int* __restrict__ csr_src) {
    int e = blockIdx.x * TPB + threadIdx.x;
    if (e >= E) return;
    bool i64 = (*flag != 0);
    int s = load_idx(ei, e, i64);
    int d = load_idx(ei, E + e, i64);
    int pos = atomicAdd(&cursor[d], 1);
    csr_src[pos] = s;
}

__global__ void dis_kernel(const int* __restrict__ counts, float* __restrict__ dis, int n) {
    int i = blockIdx.x * TPB + threadIdx.x;
    if (i < n) dis[i] = rsqrtf((float)(counts[i] + 1));
}

__global__ void scan_block_kernel(const int* __restrict__ counts, int* __restrict__ excl,
                                  int* __restrict__ partials, int n) {
    __shared__ int tmp[TPB];
    int tid = threadIdx.x, gid = blockIdx.x * TPB + tid;
    int v = (gid < n) ? counts[gid] : 0;
    tmp[tid] = v;
    __syncthreads();
    for (int off = 1; off < TPB; off <<= 1) {
        int t = (tid >= off) ? tmp[tid - off] : 0;
        __syncthreads();
        tmp[tid] += t;
        __syncthreads();
    }
    if (gid < n) excl[gid] = tmp[tid] - v;
    if (tid == TPB - 1) partials[blockIdx.x] = tmp[TPB - 1];
}

__global__ void scan_partials_kernel(int* __restrict__ partials, int nb) {
    __shared__ int tmp[512];
    int tid = threadIdx.x;
    int v = (tid < nb) ? partials[tid] : 0;
    tmp[tid] = v;
    __syncthreads();
    for (int off = 1; off < 512; off <<= 1) {
        int t = (tid >= off) ? tmp[tid - off] : 0;
        __syncthreads();
        tmp[tid] += t;
        __syncthreads();
    }
    if (tid < nb) partials[tid] = tmp[tid] - v;
}

__global__ void add_offsets_kernel(int* __restrict__ excl, const int* __restrict__ partials,
                                   int* __restrict__ cursor, int n) {
    int i = blockIdx.x * TPB + threadIdx.x;
    if (i < n) {
        int v = excl[i] + partials[blockIdx.x];
        excl[i] = v;
        cursor[i] = v;
    }
}

#define ACC8(u, d) \
    a0 = fmaf(d, bflo(u.x), a0); a1 = fmaf(d, bfhi(u.x), a1); \
    a2 = fmaf(d, bflo(u.y), a2); a3 = fmaf(d, bfhi(u.y), a3); \
    a4 = fmaf(d, bflo(u.z), a4); a5 = fmaf(d, bfhi(u.z), a5); \
    a6 = fmaf(d, bflo(u.w), a6); a7 = fmaf(d, bfhi(u.w), a7);

// ---------- aggregation C=128 (raw h in, dis[s] folded in gather) ----------
__global__ __launch_bounds__(256) void agg128_kernel(
    const uint32* __restrict__ hs, const int* __restrict__ csr,
    const int* __restrict__ row_ptr, const int* __restrict__ counts,
    const float* __restrict__ dis, const float* __restrict__ b,
    uint32* __restrict__ out, int n)
{
    int wave = threadIdx.x >> 6;
    int lane = threadIdx.x & 63;
    int g    = lane >> 4;        // quarter 0..3
    int sl   = lane & 15;
    int node = blockIdx.x * 4 + wave;
    if (node >= n) return;

    const uint4* hsv = (const uint4*)hs;   // row = 16 uint4 (128 bf16)
    float dsc = dis[node];
    float a0 = 0.f, a1 = 0.f, a2 = 0.f, a3 = 0.f,
          a4 = 0.f, a5 = 0.f, a6 = 0.f, a7 = 0.f;
    if (g == 0) {   // self-loop: dis[d]*h[d]
        uint4 u = hsv[(size_t)node * 16 + sl];
        ACC8(u, dsc);
    }

    int start = row_ptr[node];
    int end   = start + counts[node];
    int k = start;
    for (; k + 15 < end; k += 16) {
        int base = k + (g << 2);
        int s0 = csr[base], s1 = csr[base + 1], s2 = csr[base + 2], s3 = csr[base + 3];
        float d0 = dis[s0], d1 = dis[s1], d2 = dis[s2], d3 = dis[s3];
        uint4 u0 = hsv[(size_t)s0 * 16 + sl];
        uint4 u1 = hsv[(size_t)s1 * 16 + sl];
        uint4 u2 = hsv[(size_t)s2 * 16 + sl];
        uint4 u3 = hsv[(size_t)s3 * 16 + sl];
        ACC8(u0, d0); ACC8(u1, d1); ACC8(u2, d2); ACC8(u3, d3);
    }
    for (; k + 7 < end; k += 8) {
        int base = k + (g << 1);
        int s0 = csr[base], s1 = csr[base + 1];
        float d0 = dis[s0], d1 = dis[s1];
        uint4 u0 = hsv[(size_t)s0 * 16 + sl];
        uint4 u1 = hsv[(size_t)s1 * 16 + sl];
        ACC8(u0, d0); ACC8(u1, d1);
    }
    for (; k < end; k += 4) {
        int e = k + g;
        if (e < end) {
            int s0 = csr[e];
            float d0 = dis[s0];
            uint4 u = hsv[(size_t)s0 * 16 + sl];
            ACC8(u, d0);
        }
    }

    a0 += __shfl_xor(a0, 16, 64); a0 += __shfl_xor(a0, 32, 64);
    a1 += __shfl_xor(a1, 16, 64); a1 += __shfl_xor(a1, 32, 64);
    a2 += __shfl_xor(a2, 16, 64); a2 += __shfl_xor(a2, 32, 64);
    a3 += __shfl_xor(a3, 16, 64); a3 += __shfl_xor(a3, 32, 64);
    a4 += __shfl_xor(a4, 16, 64); a4 += __shfl_xor(a4, 32, 64);
    a5 += __shfl_xor(a5, 16, 64); a5 += __shfl_xor(a5, 32, 64);
    a6 += __shfl_xor(a6, 16, 64); a6 += __shfl_xor(a6, 32, 64);
    a7 += __shfl_xor(a7, 16, 64); a7 += __shfl_xor(a7, 32, 64);

    if (g == 0) {
        float4 bb0 = ((const float4*)b)[sl * 2];
        float4 bb1 = ((const float4*)b)[sl * 2 + 1];
        float v0 = fmaxf(a0 * dsc + bb0.x, 0.0f);
        float v1 = fmaxf(a1 * dsc + bb0.y, 0.0f);
        float v2 = fmaxf(a2 * dsc + bb0.z, 0.0f);
        float v3 = fmaxf(a3 * dsc + bb0.w, 0.0f);
        float v4 = fmaxf(a4 * dsc + bb1.x, 0.0f);
        float v5 = fmaxf(a5 * dsc + bb1.y, 0.0f);
        float v6 = fmaxf(a6 * dsc + bb1.z, 0.0f);
        float v7 = fmaxf(a7 * dsc + bb1.w, 0.0f);
        uint4 o;
        o.x = packbf(v0, v1); o.y = packbf(v2, v3);
        o.z = packbf(v4, v5); o.w = packbf(v6, v7);
        ((uint4*)out)[(size_t)node * 16 + sl] = o;
    }
}

// ---------- aggregation C=64 (hs2 has dis folded), eighth-wave per edge ----------
__global__ __launch_bounds__(256) void agg64_kernel(
    const uint32* __restrict__ hs, const int* __restrict__ csr,
    const int* __restrict__ row_ptr, const int* __restrict__ counts,
    const float* __restrict__ dis, const float* __restrict__ b,
    float* __restrict__ out, int n)
{
    int wave = threadIdx.x >> 6;
    int lane = threadIdx.x & 63;
    int g    = lane >> 3;        // eighth 0..7
    int sl   = lane & 7;
    int node = blockIdx.x * 4 + wave;
    if (node >= n) return;

    const uint4* hsv = (const uint4*)hs;   // row = 8 uint4 (64 bf16)
    float a0 = 0.f, a1 = 0.f, a2 = 0.f, a3 = 0.f,
          a4 = 0.f, a5 = 0.f, a6 = 0.f, a7 = 0.f;
    if (g == 0) {
        uint4 u = hsv[(size_t)node * 8 + sl];
        ACC8(u, 1.0f);
    }

    int start = row_ptr[node];
    int end   = start + counts[node];
    int k = start;
    for (; k + 15 < end; k += 16) {
        int base = k + (g << 1);
        int s0 = csr[base], s1 = csr[base + 1];
        uint4 u0 = hsv[(size_t)s0 * 8 + sl];
        uint4 u1 = hsv[(size_t)s1 * 8 + sl];
        ACC8(u0, 1.0f); ACC8(u1, 1.0f);
    }
    for (; k + 7 < end; k += 8) {
        int e = k + g;
        uint4 u = hsv[(size_t)csr[e] * 8 + sl];
        ACC8(u, 1.0f);
    }
    for (; k < end; k += 8) {
        int e = k + g;
        if (e < end) {
            uint4 u = hsv[(size_t)csr[e] * 8 + sl];
            ACC8(u, 1.0f);
        }
    }

    a0 += __shfl_xor(a0, 8, 64); a0 += __shfl_xor(a0, 16, 64); a0 += __shfl_xor(a0, 32, 64);
    a1 += __shfl_xor(a1, 8, 64); a1 += __shfl_xor(a1, 16, 64); a1 += __shfl_xor(a1, 32, 64);
    a2 += __shfl_xor(a2, 8, 64); a2 += __shfl_xor(a2, 16, 64); a2 += __shfl_xor(a2, 32, 64);
    a3 += __shfl_xor(a3, 8, 64); a3 += __shfl_xor(a3, 16, 64); a3 += __shfl_xor(a3, 32, 64);
    a4 += __shfl_xor(a4, 8, 64); a4 += __shfl_xor(a4, 16, 64); a4 += __shfl_xor(a4, 32, 64);
    a5 += __shfl_xor(a5, 8, 64); a5 += __shfl_xor(a5, 16, 64); a5 += __shfl_xor(a5, 32, 64);
    a6 += __shfl_xor(a6, 8, 64); a6 += __shfl_xor(a6, 16, 64); a6 += __shfl_xor(a6, 32, 64);
    a7 += __shfl_xor(a7, 8, 64); a7 += __shfl_xor(a7, 16, 64); a7 += __shfl_xor(a7, 32, 64);

    if (g == 0) {
        float dsc = dis[node];
        float4 bb0 = ((const float4*)b)[sl * 2];
        float4 bb1 = ((const float4*)b)[sl * 2 + 1];
        float4 o0, o1;
        o0.x = 0.1f + 0.8f / (1.0f + __expf(-(a0 * dsc + bb0.x)));
        o0.y = 0.1f + 0.8f / (1.0f + __expf(-(a1 * dsc + bb0.y)));
        o0.z = 0.1f + 0.8f / (1.0f + __expf(-(a2 * dsc + bb0.z)));
        o0.w = 0.1f + 0.8f / (1.0f + __expf(-(a3 * dsc + bb0.w)));
        o1.x = 0.1f + 0.8f / (1.0f + __expf(-(a4 * dsc + bb1.x)));
        o1.y = 0.1f + 0.8f / (1.0f + __expf(-(a5 * dsc + bb1.y)));
        o1.z = 0.1f + 0.8f / (1.0f + __expf(-(a6 * dsc + bb1.z)));
        o1.w = 0.1f + 0.8f / (1.0f + __expf(-(a7 * dsc + bb1.w)));
        ((float4*)out)[(size_t)node * 16 + sl * 2]     = o0;
        ((float4*)out)[(size_t)node * 16 + sl * 2 + 1] = o1;
    }
}

extern "C" void kernel_launch(void* const* d_in, const int* in_sizes, int n_in,
                              void* d_out, int out_size, void* d_ws, size_t ws_size,
                              hipStream_t stream) {
    const float* x  = (const float*)d_in[0];
    const void*  ei = d_in[1];
    const float* W1 = (const float*)d_in[2];
    const float* b1 = (const float*)d_in[3];
    const float* W2 = (const float*)d_in[4];
    const float* b2 = (const float*)d_in[5];

    const int N = in_sizes[0] / IN_F;   // 100000
    const int E = in_sizes[1] / 2;      // 1600000

    const int nbuckets = (N + 255) >> 8;                 // 391
    const int bcap     = (int)(2 * ((long long)E / (nbuckets > 0 ? nbuckets : 1)) + 2048);
    const bool bucketed = (nbuckets <= MAXBK);

    auto alignup = [](size_t v) { return (v + 255) & ~(size_t)255; };
    char* w = (char*)d_ws;
    size_t off = 0;
    int*      flag     = (int*)(w + off);      off = alignup(off + 16);
    int*      counts   = (int*)(w + off);      off = alignup(off + (size_t)(N + MAXBK) * sizeof(int));
    int*      bcur     = counts + N;           // contiguous with counts (R2 lesson)
    ushort16* W1t      = (ushort16*)(w + off); off = alignup(off + 128 * 128 * sizeof(ushort16));
    ushort16* W2t      = (ushort16*)(w + off); off = alignup(off + 64 * 128 * sizeof(ushort16));
    int*      cursor   = (int*)(w + off);      off = alignup(off + (size_t)N * sizeof(int));
    int*      row_ptr  = (int*)(w + off);      off = alignup(off + (size_t)N * sizeof(int));
    int*      partials = (int*)(w + off);      off = alignup(off + 512 * sizeof(int));
    float*    dis      = (float*)(w + off);    off = alignup(off + (size_t)N * sizeof(float));
    int*      csr      = (int*)(w + off);      off = alignup(off + (size_t)E * sizeof(int));
    uint32*   bbuf     = (uint32*)(w + off);   off = alignup(off + (size_t)nbuckets * bcap * sizeof(uint32));
    uint32*   A        = (uint32*)(w + off);   off = alignup(off + (size_t)N * HID * sizeof(ushort16));
    uint32*   B        = (uint32*)(w + off);   off = alignup(off + (size_t)N * HID * sizeof(ushort16));

    const int nbN = (N + TPB - 1) / TPB;   // 391
    const int nbE = (E + TPB - 1) / TPB;
    const int gemmBlocks = (N + 63) / 64;  // 1563
    const int prepBlocks = 1 + (128 * 128 + 128 * 64 + TPB - 1) / TPB;

    // prep: detect + zero bcur + transpose weights to bf16 [c][k]
    prep_kernel<<<prepBlocks, TPB, 0, stream>>>((const uint32*)ei, flag, bcur, W1, W2, W1t, W2t);

    if (bucketed) {
        const int PB = (E + PT_TILE - 1) / PT_TILE;     // 782 partition blocks
        // mega1: partition (19.5 KB LDS, 8 blk/CU) CONCURRENT with LDS-free layer-1 GEMM
        mega1_kernel<<<PB + gemmBlocks, TPB, 0, stream>>>(
            ei, E, flag, nbuckets, bcap, bcur, bbuf, x, W1t, (ushort16*)A, N, PB);
        // fused bbase-scan + degree/dis/row_ptr + CSR fill
        bucket_build_kernel<<<nbuckets, TPB, 0, stream>>>(
            bbuf, bcur, counts, dis, row_ptr, csr, N, nbuckets, bcap);
    } else {
        hipMemsetAsync(counts, 0, (size_t)(N + MAXBK) * sizeof(int), stream);
        hist_kernel<<<nbE, TPB, 0, stream>>>(ei, E, flag, counts);
        dis_kernel<<<nbN, TPB, 0, stream>>>(counts, dis, N);
        scan_block_kernel<<<nbN, TPB, 0, stream>>>(counts, row_ptr, partials, N);
        scan_partials_kernel<<<1, 512, 0, stream>>>(partials, nbN);
        add_offsets_kernel<<<nbN, TPB, 0, stream>>>(row_ptr, partials, cursor, N);
        fill_kernel<<<nbE, TPB, 0, stream>>>(ei, E, flag, cursor, csr);
        gemm_global_kernel<HID, false, false><<<gemmBlocks, TPB, 0, stream>>>(x, W1t, dis, (ushort16*)A, N);
    }

    // ---- layer 1 aggregation: h1 = relu(dis*(dis*h[d] + sum dis[s]h[s]) + b1)
    agg128_kernel<<<(N + 3) / 4, TPB, 0, stream>>>(A, csr, row_ptr, counts, dis, b1, B, N);

    // ---- layer 2: hs2 = bf16((h1@W2)*dis) ; out = 0.1+0.8*sigmoid(dis*(hs2[d]+sum hs2[s])+b2)
    gemm_global_kernel<OUTF, true, true><<<gemmBlocks, TPB, 0, stream>>>(B, W2t, dis, (ushort16*)A, N);
    agg64_kernel<<<(N + 3) / 4, TPB, 0, stream>>>(A, csr, row_ptr, counts, dis, b2, (float*)d_out, N);
}

// Round 12
// 196.221 us; speedup vs baseline: 1.1315x; 1.1315x over previous
//
#include <hip/hip_runtime.h>
#include <cstdint>
#include <cstddef>

#define IN_F 128
#define HID  128
#define OUTF 64

typedef unsigned int   uint32;
typedef unsigned short ushort16;

using frag_ab = __attribute__((ext_vector_type(8))) short;   // 8 bf16
using frag_cd = __attribute__((ext_vector_type(4))) float;   // 4 f32

static constexpr int TPB = 256;
static constexpr int PT_TILE = 2048;    // edges per partition block
static constexpr int PT_EPT  = 8;       // edges per thread
static constexpr int MAXBK   = 512;     // max buckets (N <= 131072) for bucketed path
static constexpr int PART_SMEM = 19456; // partition LDS; gemm halves use 17408 <= this

// ---------- bf16 helpers (RNE) ----------
__device__ __forceinline__ float bflo(uint32 u) { return __uint_as_float(u << 16); }
__device__ __forceinline__ float bfhi(uint32 u) { return __uint_as_float(u & 0xFFFF0000u); }
__device__ __forceinline__ ushort16 f2bf(float f) {
    uint32 x = __float_as_uint(f);
    x = (x + 0x7FFFu + ((x >> 16) & 1u)) >> 16;
    return (ushort16)x;
}
__device__ __forceinline__ uint32 packbf(float a, float b) {
    return (uint32)f2bf(a) | ((uint32)f2bf(b) << 16);
}

__device__ __forceinline__ int load_idx(const void* p, int i, bool i64) {
    return i64 ? (int)((const long long*)p)[i] : ((const int*)p)[i];
}

// ---------- prep: detect idx dtype + zero bcur + transpose W1/W2 to bf16 [c][k] ----------
__global__ void prep_kernel(const uint32* __restrict__ p, int* __restrict__ flag,
                            int* __restrict__ bcur,
                            const float* __restrict__ W1, const float* __restrict__ W2,
                            ushort16* __restrict__ W1t, ushort16* __restrict__ W2t)
{
    int tid = threadIdx.x;
    if (blockIdx.x == 0) {
        __shared__ int anynz;
        if (tid == 0) anynz = 0;
        __syncthreads();
        if (p[2 * tid + 1] != 0u) atomicOr(&anynz, 1);
        bcur[tid] = 0; bcur[tid + 256] = 0;
        __syncthreads();
        if (tid == 0) *flag = (anynz == 0) ? 1 : 0;
        return;
    }
    int i = (blockIdx.x - 1) * TPB + tid;
    if (i < 128 * 128) {
        int k = i >> 7, c = i & 127;
        W1t[c * 128 + k] = f2bf(W1[i]);
    } else {
        int j = i - 128 * 128;
        if (j < 128 * 64) {
            int k = j >> 6, c = j & 63;
            W2t[c * 128 + k] = f2bf(W2[j]);
        }
    }
}

// ---------- MFMA GEMM body with HALF-W LDS staging (17408 B <= PART_SMEM) ----------
// Wt: bf16 [col][k=128] in global (from prep). Stage 64 cols at a time into
// Wl[64][136] (pad 136 -> b128 start-bank = 4*li mod 32, 2-way aliasing = free).
// A-fragments preloaded to regs so both halves reuse them. R11 lesson: W fragment
// reads MUST come from LDS (~15cy), not global (~200cy) — MFMA starves otherwise.
template <int C, bool XBF, bool SCALE>
__device__ __forceinline__ void gemm_lds_body(
    char* smem, int gb, const void* __restrict__ Xv, const ushort16* __restrict__ Wt,
    const float* __restrict__ dis, ushort16* __restrict__ out, int M)
{
    constexpr int NB     = C / 16;   // 8 or 4 col-tiles
    constexpr int HALVES = C / 64;   // 2 or 1
    typedef ushort16 Row[136];
    Row* Wl = (Row*)smem;

    int tid  = threadIdx.x;
    int wid  = tid >> 6;
    int lane = tid & 63;
    int g    = lane >> 4;
    int li   = lane & 15;

    int row = gb * 64 + wid * 16 + li;
    int rc  = min(row, M - 1);

    frag_ab af[4];
#pragma unroll
    for (int t = 0; t < 4; ++t) {
        if (XBF) {
            const ushort16* xp = (const ushort16*)Xv + (size_t)rc * 128 + t * 32 + g * 8;
            af[t] = *(const frag_ab*)xp;
        } else {
            const float* xp = (const float*)Xv + (size_t)rc * 128 + t * 32 + g * 8;
            float4 pp = *(const float4*)xp;
            float4 qq = *(const float4*)(xp + 4);
            frag_ab a;
            a[0] = (short)f2bf(pp.x); a[1] = (short)f2bf(pp.y);
            a[2] = (short)f2bf(pp.z); a[3] = (short)f2bf(pp.w);
            a[4] = (short)f2bf(qq.x); a[5] = (short)f2bf(qq.y);
            a[6] = (short)f2bf(qq.z); a[7] = (short)f2bf(qq.w);
            af[t] = a;
        }
    }

    frag_cd acc[NB];
#pragma unroll
    for (int i = 0; i < NB; ++i) acc[i] = (frag_cd)0.0f;

#pragma unroll
    for (int half = 0; half < HALVES; ++half) {
        if (half > 0) __syncthreads();   // prior half's reads done before overwrite
        // stage 64 cols x 128 k (16 KB): 1024 uint4, 4 per thread, coalesced
        for (int i = tid; i < 64 * 16; i += 256) {
            int r = i >> 4, c4 = i & 15;
            ((uint4*)&Wl[r][0])[c4] =
                ((const uint4*)(Wt + (size_t)(half * 64 + r) * 128))[c4];
        }
        __syncthreads();
#pragma unroll
        for (int t = 0; t < 4; ++t) {
#pragma unroll
            for (int cb = 0; cb < 4; ++cb) {
                frag_ab b = *(const frag_ab*)&Wl[cb * 16 + li][t * 32 + g * 8];
                acc[half * 4 + cb] =
                    __builtin_amdgcn_mfma_f32_16x16x32_bf16(af[t], b, acc[half * 4 + cb], 0, 0, 0);
            }
        }
    }

    int ro = gb * 64 + wid * 16 + g * 4;
#pragma unroll
    for (int r = 0; r < 4; ++r) {
        int rr = ro + r;
        if (rr < M) {
            float dsc = SCALE ? dis[rr] : 1.0f;
#pragma unroll
            for (int cb = 0; cb < NB; ++cb)
                out[(size_t)rr * C + cb * 16 + li] = f2bf(acc[cb][r] * dsc);
        }
    }
}

template <int C, bool XBF, bool SCALE>
__global__ __launch_bounds__(256) void gemm_lds_kernel(
    const void* __restrict__ Xv, const ushort16* __restrict__ Wt,
    const float* __restrict__ dis, ushort16* __restrict__ out, int M)
{
    __shared__ char smem[17408];
    gemm_lds_body<C, XBF, SCALE>(smem, blockIdx.x, Xv, Wt, dis, out, M);
}

// ---------- partition body (19.5 KB LDS) ----------
__device__ void partition_body(char* smem, const void* __restrict__ ei, int E, bool i64,
                               int nbuckets, int bcap,
                               int* __restrict__ bcur, uint32* __restrict__ bbuf)
{
    uint32*   stash  = (uint32*)smem;                 // 8192 B
    ushort16* bidx   = (ushort16*)(smem + 8192);      // 4096 B
    int*      hist   = (int*)(smem + 12288);          // 2048 B
    int*      scanb  = (int*)(smem + 14336);          // 2048 B
    int*      gbase  = (int*)(smem + 16384);          // 2048 B
    int*      sum256 = (int*)(smem + 18432);          // 1024 B

    int tile0 = blockIdx.x * PT_TILE;
    int tid = threadIdx.x;

    for (int i = tid; i < nbuckets; i += 256) hist[i] = 0;
    __syncthreads();

    uint32 pck[PT_EPT];
    int    lofs[PT_EPT];
    short  bkt[PT_EPT];
#pragma unroll
    for (int j = 0; j < PT_EPT; ++j) {
        int e = tile0 + j * 256 + tid;
        if (e < E) {
            int s = load_idx(ei, e, i64);
            int d = load_idx(ei, E + e, i64);
            int b = d >> 8;
            pck[j]  = (uint32)s | ((uint32)(d & 255) << 24);
            bkt[j]  = (short)b;
            lofs[j] = atomicAdd(&hist[b], 1);
        } else bkt[j] = -1;
    }
    __syncthreads();

    for (int i = tid; i < nbuckets; i += 256)
        gbase[i] = hist[i] ? atomicAdd(&bcur[i], hist[i]) : 0;

    {   // exclusive scan of hist (2 elems/thread, MAXBK=512)
        int lt = tid * 2;
        int h0 = 0, h1 = 0;
        if (lt + 0 < nbuckets) h0 = hist[lt + 0];
        if (lt + 1 < nbuckets) h1 = hist[lt + 1];
        int lsum = h0 + h1;
        sum256[tid] = lsum;
        __syncthreads();
        for (int off = 1; off < 256; off <<= 1) {
            int t = (tid >= off) ? sum256[tid - off] : 0;
            __syncthreads();
            sum256[tid] += t;
            __syncthreads();
        }
        int excl = sum256[tid] - lsum;
        if (lt + 0 < nbuckets) scanb[lt + 0] = excl;
        if (lt + 1 < nbuckets) scanb[lt + 1] = excl + h0;
    }
    __syncthreads();

#pragma unroll
    for (int j = 0; j < PT_EPT; ++j) {
        if (bkt[j] >= 0) {
            int p = scanb[bkt[j]] + lofs[j];
            stash[p] = pck[j];
            bidx[p]  = (ushort16)bkt[j];
        }
    }
    __syncthreads();

    int total = min(PT_TILE, E - tile0);
    for (int k = tid; k < total; k += 256) {
        int b = bidx[k];
        int dst = gbase[b] + (k - scanb[b]);
        if (dst < bcap) bbuf[(size_t)b * bcap + dst] = stash[k];
    }
}

// ---------- mega1: blocks [0,PB) partition ; blocks [PB,..) raw layer-1 GEMM (LDS-staged) ----------
__global__ __launch_bounds__(256) void mega1_kernel(
    const void* __restrict__ ei, int E, const int* __restrict__ flag,
    int nbuckets, int bcap, int* __restrict__ bcur, uint32* __restrict__ bbuf,
    const float* __restrict__ X, const ushort16* __restrict__ W1t,
    ushort16* __restrict__ H, int M, int PB)
{
    __shared__ char smem[PART_SMEM];
    if ((int)blockIdx.x < PB) {
        partition_body(smem, ei, E, (*flag != 0), nbuckets, bcap, bcur, bbuf);
    } else {
        gemm_lds_body<HID, false, false>(smem, blockIdx.x - PB, X, W1t, nullptr, H, M);
    }
}

// ---------- bucket_build: bbase scan + degree/dis/row_ptr + CSR fill, one kernel ----------
__global__ __launch_bounds__(256) void bucket_build_kernel(
    const uint32* __restrict__ bbuf, const int* __restrict__ bcur,
    int* __restrict__ counts, float* __restrict__ dis, int* __restrict__ row_ptr,
    int* __restrict__ csr, int N, int nbuckets, int bcap)
{
    __shared__ int pcnt[512];
    __shared__ int pinc[256];
    __shared__ int h[256];
    __shared__ int sc[256];
    __shared__ int cur[256];

    int tid = threadIdx.x;
    int b = blockIdx.x;

    pcnt[tid]       = (tid < nbuckets)       ? min(bcur[tid], bcap)       : 0;
    pcnt[tid + 256] = (tid + 256 < nbuckets) ? min(bcur[tid + 256], bcap) : 0;
    h[tid] = 0;
    __syncthreads();
    int ps = pcnt[2 * tid] + pcnt[2 * tid + 1];
    pinc[tid] = ps;
    __syncthreads();
    for (int off = 1; off < 256; off <<= 1) {
        int t = (tid >= off) ? pinc[tid - off] : 0;
        __syncthreads();
        pinc[tid] += t;
        __syncthreads();
    }
    int p2 = b >> 1;
    int bbase = pinc[p2] - (pcnt[2 * p2] + pcnt[2 * p2 + 1]) + ((b & 1) ? pcnt[b - 1] : 0);

    int cnt = min(bcur[b], bcap);
    const uint32* src = bbuf + (size_t)b * bcap;
    for (int k = tid; k < cnt; k += 256) atomicAdd(&h[src[k] >> 24], 1);
    __syncthreads();

    int v = h[tid];
    sc[tid] = v;
    __syncthreads();
    for (int off = 1; off < 256; off <<= 1) {
        int t = (tid >= off) ? sc[tid - off] : 0;
        __syncthreads();
        sc[tid] += t;
        __syncthreads();
    }
    int myrow = bbase + sc[tid] - v;
    int node = (b << 8) + tid;
    if (node < N) {
        counts[node]  = v;
        dis[node]     = rsqrtf((float)(v + 1));   // +1 self-loop
        row_ptr[node] = myrow;
    }
    cur[tid] = myrow;
    __syncthreads();

    for (int k = tid; k < cnt; k += 256) {
        uint32 p = src[k];
        int dl = p >> 24;
        int pos = atomicAdd(&cur[dl], 1);
        csr[pos] = (int)(p & 0xFFFFFF);
    }
}

// ---------- legacy build path (N too large for bucketed path) ----------
__global__ void hist_kernel(const void* __restrict__ ei, int E, const int* __restrict__ flag,
                            int* __restrict__ counts) {
    int e = blockIdx.x * TPB + threadIdx.x;
    if (e >= E) return;
    bool i64 = (*flag != 0);
    atomicAdd(&counts[load_idx(ei, E + e, i64)], 1);
}

__global__ void fill_kernel(const void* __restrict__ ei, int E, const int* __restrict__ flag,
                            int* __restrict__ cursor, int* __restrict__ csr_src) {
    int e = blockIdx.x * TPB + threadIdx.x;
    if (e >= E) return;
    bool i64 = (*flag != 0);
    int s = load_idx(ei, e, i64);
    int d = load_idx(ei, E + e, i64);
    int pos = atomicAdd(&cursor[d], 1);
    csr_src[pos] = s;
}

__global__ void dis_kernel(const int* __restrict__ counts, float* __restrict__ dis, int n) {
    int i = blockIdx.x * TPB + threadIdx.x;
    if (i < n) dis[i] = rsqrtf((float)(counts[i] + 1));
}

__global__ void scan_block_kernel(const int* __restrict__ counts, int* __restrict__ excl,
                                  int* __restrict__ partials, int n) {
    __shared__ int tmp[TPB];
    int tid = threadIdx.x, gid = blockIdx.x * TPB + tid;
    int v = (gid < n) ? counts[gid] : 0;
    tmp[tid] = v;
    __syncthreads();
    for (int off = 1; off < TPB; off <<= 1) {
        int t = (tid >= off) ? tmp[tid - off] : 0;
        __syncthreads();
        tmp[tid] += t;
        __syncthreads();
    }
    if (gid < n) excl[gid] = tmp[tid] - v;
    if (tid == TPB - 1) partials[blockIdx.x] = tmp[TPB - 1];
}

__global__ void scan_partials_kernel(int* __restrict__ partials, int nb) {
    __shared__ int tmp[512];
    int tid = threadIdx.x;
    int v = (tid < nb) ? partials[tid] : 0;
    tmp[tid] = v;
    __syncthreads();
    for (int off = 1; off < 512; off <<= 1) {
        int t = (tid >= off) ? tmp[tid - off] : 0;
        __syncthreads();
        tmp[tid] += t;
        __syncthreads();
    }
    if (tid < nb) partials[tid] = tmp[tid] - v;
}

__global__ void add_offsets_kernel(int* __restrict__ excl, const int* __restrict__ partials,
                                   int* __restrict__ cursor, int n) {
    int i = blockIdx.x * TPB + threadIdx.x;
    if (i < n) {
        int v = excl[i] + partials[blockIdx.x];
        excl[i] = v;
        cursor[i] = v;
    }
}

#define ACC8(u, d) \
    a0 = fmaf(d, bflo(u.x), a0); a1 = fmaf(d, bfhi(u.x), a1); \
    a2 = fmaf(d, bflo(u.y), a2); a3 = fmaf(d, bfhi(u.y), a3); \
    a4 = fmaf(d, bflo(u.z), a4); a5 = fmaf(d, bfhi(u.z), a5); \
    a6 = fmaf(d, bflo(u.w), a6); a7 = fmaf(d, bfhi(u.w), a7);

// ---------- aggregation C=128 (raw h in, dis[s] folded in gather) ----------
__global__ __launch_bounds__(256) void agg128_kernel(
    const uint32* __restrict__ hs, const int* __restrict__ csr,
    const int* __restrict__ row_ptr, const int* __restrict__ counts,
    const float* __restrict__ dis, const float* __restrict__ b,
    uint32* __restrict__ out, int n)
{
    int wave = threadIdx.x >> 6;
    int lane = threadIdx.x & 63;
    int g    = lane >> 4;        // quarter 0..3
    int sl   = lane & 15;
    int node = blockIdx.x * 4 + wave;
    if (node >= n) return;

    const uint4* hsv = (const uint4*)hs;   // row = 16 uint4 (128 bf16)
    float dsc = dis[node];
    float a0 = 0.f, a1 = 0.f, a2 = 0.f, a3 = 0.f,
          a4 = 0.f, a5 = 0.f, a6 = 0.f, a7 = 0.f;
    if (g == 0) {   // self-loop: dis[d]*h[d]
        uint4 u = hsv[(size_t)node * 16 + sl];
        ACC8(u, dsc);
    }

    int start = row_ptr[node];
    int end   = start + counts[node];
    int k = start;
    for (; k + 15 < end; k += 16) {
        int base = k + (g << 2);
        int s0 = csr[base], s1 = csr[base + 1], s2 = csr[base + 2], s3 = csr[base + 3];
        float d0 = dis[s0], d1 = dis[s1], d2 = dis[s2], d3 = dis[s3];
        uint4 u0 = hsv[(size_t)s0 * 16 + sl];
        uint4 u1 = hsv[(size_t)s1 * 16 + sl];
        uint4 u2 = hsv[(size_t)s2 * 16 + sl];
        uint4 u3 = hsv[(size_t)s3 * 16 + sl];
        ACC8(u0, d0); ACC8(u1, d1); ACC8(u2, d2); ACC8(u3, d3);
    }
    for (; k + 7 < end; k += 8) {
        int base = k + (g << 1);
        int s0 = csr[base], s1 = csr[base + 1];
        float d0 = dis[s0], d1 = dis[s1];
        uint4 u0 = hsv[(size_t)s0 * 16 + sl];
        uint4 u1 = hsv[(size_t)s1 * 16 + sl];
        ACC8(u0, d0); ACC8(u1, d1);
    }
    for (; k < end; k += 4) {
        int e = k + g;
        if (e < end) {
            int s0 = csr[e];
            float d0 = dis[s0];
            uint4 u = hsv[(size_t)s0 * 16 + sl];
            ACC8(u, d0);
        }
    }

    a0 += __shfl_xor(a0, 16, 64); a0 += __shfl_xor(a0, 32, 64);
    a1 += __shfl_xor(a1, 16, 64); a1 += __shfl_xor(a1, 32, 64);
    a2 += __shfl_xor(a2, 16, 64); a2 += __shfl_xor(a2, 32, 64);
    a3 += __shfl_xor(a3, 16, 64); a3 += __shfl_xor(a3, 32, 64);
    a4 += __shfl_xor(a4, 16, 64); a4 += __shfl_xor(a4, 32, 64);
    a5 += __shfl_xor(a5, 16, 64); a5 += __shfl_xor(a5, 32, 64);
    a6 += __shfl_xor(a6, 16, 64); a6 += __shfl_xor(a6, 32, 64);
    a7 += __shfl_xor(a7, 16, 64); a7 += __shfl_xor(a7, 32, 64);

    if (g == 0) {
        float4 bb0 = ((const float4*)b)[sl * 2];
        float4 bb1 = ((const float4*)b)[sl * 2 + 1];
        float v0 = fmaxf(a0 * dsc + bb0.x, 0.0f);
        float v1 = fmaxf(a1 * dsc + bb0.y, 0.0f);
        float v2 = fmaxf(a2 * dsc + bb0.z, 0.0f);
        float v3 = fmaxf(a3 * dsc + bb0.w, 0.0f);
        float v4 = fmaxf(a4 * dsc + bb1.x, 0.0f);
        float v5 = fmaxf(a5 * dsc + bb1.y, 0.0f);
        float v6 = fmaxf(a6 * dsc + bb1.z, 0.0f);
        float v7 = fmaxf(a7 * dsc + bb1.w, 0.0f);
        uint4 o;
        o.x = packbf(v0, v1); o.y = packbf(v2, v3);
        o.z = packbf(v4, v5); o.w = packbf(v6, v7);
        ((uint4*)out)[(size_t)node * 16 + sl] = o;
    }
}

// ---------- aggregation C=64 (hs2 has dis folded), eighth-wave per edge ----------
__global__ __launch_bounds__(256) void agg64_kernel(
    const uint32* __restrict__ hs, const int* __restrict__ csr,
    const int* __restrict__ row_ptr, const int* __restrict__ counts,
    const float* __restrict__ dis, const float* __restrict__ b,
    float* __restrict__ out, int n)
{
    int wave = threadIdx.x >> 6;
    int lane = threadIdx.x & 63;
    int g    = lane >> 3;        // eighth 0..7
    int sl   = lane & 7;
    int node = blockIdx.x * 4 + wave;
    if (node >= n) return;

    const uint4* hsv = (const uint4*)hs;   // row = 8 uint4 (64 bf16)
    float a0 = 0.f, a1 = 0.f, a2 = 0.f, a3 = 0.f,
          a4 = 0.f, a5 = 0.f, a6 = 0.f, a7 = 0.f;
    if (g == 0) {
        uint4 u = hsv[(size_t)node * 8 + sl];
        ACC8(u, 1.0f);
    }

    int start = row_ptr[node];
    int end   = start + counts[node];
    int k = start;
    for (; k + 15 < end; k += 16) {
        int base = k + (g << 1);
        int s0 = csr[base], s1 = csr[base + 1];
        uint4 u0 = hsv[(size_t)s0 * 8 + sl];
        uint4 u1 = hsv[(size_t)s1 * 8 + sl];
        ACC8(u0, 1.0f); ACC8(u1, 1.0f);
    }
    for (; k + 7 < end; k += 8) {
        int e = k + g;
        uint4 u = hsv[(size_t)csr[e] * 8 + sl];
        ACC8(u, 1.0f);
    }
    for (; k < end; k += 8) {
        int e = k + g;
        if (e < end) {
            uint4 u = hsv[(size_t)csr[e] * 8 + sl];
            ACC8(u, 1.0f);
        }
    }

    a0 += __shfl_xor(a0, 8, 64); a0 += __shfl_xor(a0, 16, 64); a0 += __shfl_xor(a0, 32, 64);
    a1 += __shfl_xor(a1, 8, 64); a1 += __shfl_xor(a1, 16, 64); a1 += __shfl_xor(a1, 32, 64);
    a2 += __shfl_xor(a2, 8, 64); a2 += __shfl_xor(a2, 16, 64); a2 += __shfl_xor(a2, 32, 64);
    a3 += __shfl_xor(a3, 8, 64); a3 += __shfl_xor(a3, 16, 64); a3 += __shfl_xor(a3, 32, 64);
    a4 += __shfl_xor(a4, 8, 64); a4 += __shfl_xor(a4, 16, 64); a4 += __shfl_xor(a4, 32, 64);
    a5 += __shfl_xor(a5, 8, 64); a5 += __shfl_xor(a5, 16, 64); a5 += __shfl_xor(a5, 32, 64);
    a6 += __shfl_xor(a6, 8, 64); a6 += __shfl_xor(a6, 16, 64); a6 += __shfl_xor(a6, 32, 64);
    a7 += __shfl_xor(a7, 8, 64); a7 += __shfl_xor(a7, 16, 64); a7 += __shfl_xor(a7, 32, 64);

    if (g == 0) {
        float dsc = dis[node];
        float4 bb0 = ((const float4*)b)[sl * 2];
        float4 bb1 = ((const float4*)b)[sl * 2 + 1];
        float4 o0, o1;
        o0.x = 0.1f + 0.8f / (1.0f + __expf(-(a0 * dsc + bb0.x)));
        o0.y = 0.1f + 0.8f / (1.0f + __expf(-(a1 * dsc + bb0.y)));
        o0.z = 0.1f + 0.8f / (1.0f + __expf(-(a2 * dsc + bb0.z)));
        o0.w = 0.1f + 0.8f / (1.0f + __expf(-(a3 * dsc + bb0.w)));
        o1.x = 0.1f + 0.8f / (1.0f + __expf(-(a4 * dsc + bb1.x)));
        o1.y = 0.1f + 0.8f / (1.0f + __expf(-(a5 * dsc + bb1.y)));
        o1.z = 0.1f + 0.8f / (1.0f + __expf(-(a6 * dsc + bb1.z)));
        o1.w = 0.1f + 0.8f / (1.0f + __expf(-(a7 * dsc + bb1.w)));
        ((float4*)out)[(size_t)node * 16 + sl * 2]     = o0;
        ((float4*)out)[(size_t)node * 16 + sl * 2 + 1] = o1;
    }
}

extern "C" void kernel_launch(void* const* d_in, const int* in_sizes, int n_in,
                              void* d_out, int out_size, void* d_ws, size_t ws_size,
                              hipStream_t stream) {
    const float* x  = (const float*)d_in[0];
    const void*  ei = d_in[1];
    const float* W1 = (const float*)d_in[2];
    const float* b1 = (const float*)d_in[3];
    const float* W2 = (const float*)d_in[4];
    const float* b2 = (const float*)d_in[5];

    const int N = in_sizes[0] / IN_F;   // 100000
    const int E = in_sizes[1] / 2;      // 1600000

    const int nbuckets = (N + 255) >> 8;                 // 391
    const int bcap     = (int)(2 * ((long long)E / (nbuckets > 0 ? nbuckets : 1)) + 2048);
    const bool bucketed = (nbuckets <= MAXBK);

    auto alignup = [](size_t v) { return (v + 255) & ~(size_t)255; };
    char* w = (char*)d_ws;
    size_t off = 0;
    int*      flag     = (int*)(w + off);      off = alignup(off + 16);
    int*      counts   = (int*)(w + off);      off = alignup(off + (size_t)(N + MAXBK) * sizeof(int));
    int*      bcur     = counts + N;           // contiguous with counts (R2 lesson)
    ushort16* W1t      = (ushort16*)(w + off); off = alignup(off + 128 * 128 * sizeof(ushort16));
    ushort16* W2t      = (ushort16*)(w + off); off = alignup(off + 64 * 128 * sizeof(ushort16));
    int*      cursor   = (int*)(w + off);      off = alignup(off + (size_t)N * sizeof(int));
    int*      row_ptr  = (int*)(w + off);      off = alignup(off + (size_t)N * sizeof(int));
    int*      partials = (int*)(w + off);      off = alignup(off + 512 * sizeof(int));
    float*    dis      = (float*)(w + off);    off = alignup(off + (size_t)N * sizeof(float));
    int*      csr      = (int*)(w + off);      off = alignup(off + (size_t)E * sizeof(int));
    uint32*   bbuf     = (uint32*)(w + off);   off = alignup(off + (size_t)nbuckets * bcap * sizeof(uint32));
    uint32*   A        = (uint32*)(w + off);   off = alignup(off + (size_t)N * HID * sizeof(ushort16));
    uint32*   B        = (uint32*)(w + off);   off = alignup(off + (size_t)N * HID * sizeof(ushort16));

    const int nbN = (N + TPB - 1) / TPB;   // 391
    const int nbE = (E + TPB - 1) / TPB;
    const int gemmBlocks = (N + 63) / 64;  // 1563
    const int prepBlocks = 1 + (128 * 128 + 128 * 64 + TPB - 1) / TPB;

    prep_kernel<<<prepBlocks, TPB, 0, stream>>>((const uint32*)ei, flag, bcur, W1, W2, W1t, W2t);

    if (bucketed) {
        const int PB = (E + PT_TILE - 1) / PT_TILE;     // 782 partition blocks
        // mega1: partition (19.5 KB) CONCURRENT with layer-1 GEMM (17.4 KB LDS, 2-half W stage)
        mega1_kernel<<<PB + gemmBlocks, TPB, 0, stream>>>(
            ei, E, flag, nbuckets, bcap, bcur, bbuf, x, W1t, (ushort16*)A, N, PB);
        bucket_build_kernel<<<nbuckets, TPB, 0, stream>>>(
            bbuf, bcur, counts, dis, row_ptr, csr, N, nbuckets, bcap);
    } else {
        hipMemsetAsync(counts, 0, (size_t)(N + MAXBK) * sizeof(int), stream);
        hist_kernel<<<nbE, TPB, 0, stream>>>(ei, E, flag, counts);
        dis_kernel<<<nbN, TPB, 0, stream>>>(counts, dis, N);
        scan_block_kernel<<<nbN, TPB, 0, stream>>>(counts, row_ptr, partials, N);
        scan_partials_kernel<<<1, 512, 0, stream>>>(partials, nbN);
        add_offsets_kernel<<<nbN, TPB, 0, stream>>>(row_ptr, partials, cursor, N);
        fill_kernel<<<nbE, TPB, 0, stream>>>(ei, E, flag, cursor, csr);
        gemm_lds_kernel<HID, false, false><<<gemmBlocks, TPB, 0, stream>>>(x, W1t, dis, (ushort16*)A, N);
    }

    // ---- layer 1 aggregation: h1 = relu(dis*(dis*h[d] + sum dis[s]h[s]) + b1)
    agg128_kernel<<<(N + 3) / 4, TPB, 0, stream>>>(A, csr, row_ptr, counts, dis, b1, B, N);

    // ---- layer 2: hs2 = bf16((h1@W2)*dis) ; out = 0.1+0.8*sigmoid(dis*(hs2[d]+sum hs2[s])+b2)
    gemm_lds_kernel<OUTF, true, true><<<gemmBlocks, TPB, 0, stream>>>(B, W2t, dis, (ushort16*)A, N);
    agg64_kernel<<<(N + 3) / 4, TPB, 0, stream>>>(A, csr, row_ptr, counts, dis, b2, (float*)d_out, N);
}

// Round 13
// 193.566 us; speedup vs baseline: 1.1470x; 1.0137x over previous
//
#include <hip/hip_runtime.h>
#include <cstdint>
#include <cstddef>

#define IN_F 128
#define HID  128
#define OUTF 64

typedef unsigned int   uint32;
typedef unsigned short ushort16;

using frag_ab = __attribute__((ext_vector_type(8))) short;   // 8 bf16
using frag_cd = __attribute__((ext_vector_type(4))) float;   // 4 f32

static constexpr int TPB = 256;
static constexpr int PT_TILE = 2048;    // edges per partition block
static constexpr int PT_EPT  = 8;       // edges per thread
static constexpr int MAXBK   = 512;     // max buckets (N <= 131072) for bucketed path
static constexpr int PART_SMEM = 19456; // partition LDS; gemm halves use 17408 <= this

// ---------- bf16 helpers (RNE) ----------
__device__ __forceinline__ float bflo(uint32 u) { return __uint_as_float(u << 16); }
__device__ __forceinline__ float bfhi(uint32 u) { return __uint_as_float(u & 0xFFFF0000u); }
__device__ __forceinline__ ushort16 f2bf(float f) {
    uint32 x = __float_as_uint(f);
    x = (x + 0x7FFFu + ((x >> 16) & 1u)) >> 16;
    return (ushort16)x;
}
__device__ __forceinline__ uint32 packbf(float a, float b) {
    return (uint32)f2bf(a) | ((uint32)f2bf(b) << 16);
}

__device__ __forceinline__ int load_idx(const void* p, int i, bool i64) {
    return i64 ? (int)((const long long*)p)[i] : ((const int*)p)[i];
}

// ---------- prep: detect idx dtype + zero bcur + transpose W1/W2 to bf16 [c][k] ----------
__global__ void prep_kernel(const uint32* __restrict__ p, int* __restrict__ flag,
                            int* __restrict__ bcur,
                            const float* __restrict__ W1, const float* __restrict__ W2,
                            ushort16* __restrict__ W1t, ushort16* __restrict__ W2t)
{
    int tid = threadIdx.x;
    if (blockIdx.x == 0) {
        __shared__ int anynz;
        if (tid == 0) anynz = 0;
        __syncthreads();
        if (p[2 * tid + 1] != 0u) atomicOr(&anynz, 1);
        bcur[tid] = 0; bcur[tid + 256] = 0;
        __syncthreads();
        if (tid == 0) *flag = (anynz == 0) ? 1 : 0;
        return;
    }
    int i = (blockIdx.x - 1) * TPB + tid;
    if (i < 128 * 128) {
        int k = i >> 7, c = i & 127;
        W1t[c * 128 + k] = f2bf(W1[i]);
    } else {
        int j = i - 128 * 128;
        if (j < 128 * 64) {
            int k = j >> 6, c = j & 63;
            W2t[c * 128 + k] = f2bf(W2[j]);
        }
    }
}

// ---------- MFMA GEMM body with HALF-W LDS staging (17408 B <= PART_SMEM) ----------
template <int C, bool XBF, bool SCALE>
__device__ __forceinline__ void gemm_lds_body(
    char* smem, int gb, const void* __restrict__ Xv, const ushort16* __restrict__ Wt,
    const float* __restrict__ dis, ushort16* __restrict__ out, int M)
{
    constexpr int NB     = C / 16;   // 8 or 4 col-tiles
    constexpr int HALVES = C / 64;   // 2 or 1
    typedef ushort16 Row[136];
    Row* Wl = (Row*)smem;

    int tid  = threadIdx.x;
    int wid  = tid >> 6;
    int lane = tid & 63;
    int g    = lane >> 4;
    int li   = lane & 15;

    int row = gb * 64 + wid * 16 + li;
    int rc  = min(row, M - 1);

    frag_ab af[4];
#pragma unroll
    for (int t = 0; t < 4; ++t) {
        if (XBF) {
            const ushort16* xp = (const ushort16*)Xv + (size_t)rc * 128 + t * 32 + g * 8;
            af[t] = *(const frag_ab*)xp;
        } else {
            const float* xp = (const float*)Xv + (size_t)rc * 128 + t * 32 + g * 8;
            float4 pp = *(const float4*)xp;
            float4 qq = *(const float4*)(xp + 4);
            frag_ab a;
            a[0] = (short)f2bf(pp.x); a[1] = (short)f2bf(pp.y);
            a[2] = (short)f2bf(pp.z); a[3] = (short)f2bf(pp.w);
            a[4] = (short)f2bf(qq.x); a[5] = (short)f2bf(qq.y);
            a[6] = (short)f2bf(qq.z); a[7] = (short)f2bf(qq.w);
            af[t] = a;
        }
    }

    frag_cd acc[NB];
#pragma unroll
    for (int i = 0; i < NB; ++i) acc[i] = (frag_cd)0.0f;

#pragma unroll
    for (int half = 0; half < HALVES; ++half) {
        if (half > 0) __syncthreads();
        for (int i = tid; i < 64 * 16; i += 256) {
            int r = i >> 4, c4 = i & 15;
            ((uint4*)&Wl[r][0])[c4] =
                ((const uint4*)(Wt + (size_t)(half * 64 + r) * 128))[c4];
        }
        __syncthreads();
#pragma unroll
        for (int t = 0; t < 4; ++t) {
#pragma unroll
            for (int cb = 0; cb < 4; ++cb) {
                frag_ab b = *(const frag_ab*)&Wl[cb * 16 + li][t * 32 + g * 8];
                acc[half * 4 + cb] =
                    __builtin_amdgcn_mfma_f32_16x16x32_bf16(af[t], b, acc[half * 4 + cb], 0, 0, 0);
            }
        }
    }

    int ro = gb * 64 + wid * 16 + g * 4;
#pragma unroll
    for (int r = 0; r < 4; ++r) {
        int rr = ro + r;
        if (rr < M) {
            float dsc = SCALE ? dis[rr] : 1.0f;
#pragma unroll
            for (int cb = 0; cb < NB; ++cb)
                out[(size_t)rr * C + cb * 16 + li] = f2bf(acc[cb][r] * dsc);
        }
    }
}

template <int C, bool XBF, bool SCALE>
__global__ __launch_bounds__(256) void gemm_lds_kernel(
    const void* __restrict__ Xv, const ushort16* __restrict__ Wt,
    const float* __restrict__ dis, ushort16* __restrict__ out, int M)
{
    __shared__ char smem[17408];
    gemm_lds_body<C, XBF, SCALE>(smem, blockIdx.x, Xv, Wt, dis, out, M);
}

// ---------- partition body (19.5 KB LDS) ----------
__device__ void partition_body(char* smem, const void* __restrict__ ei, int E, bool i64,
                               int nbuckets, int bcap,
                               int* __restrict__ bcur, uint32* __restrict__ bbuf)
{
    uint32*   stash  = (uint32*)smem;                 // 8192 B
    ushort16* bidx   = (ushort16*)(smem + 8192);      // 4096 B
    int*      hist   = (int*)(smem + 12288);          // 2048 B
    int*      scanb  = (int*)(smem + 14336);          // 2048 B
    int*      gbase  = (int*)(smem + 16384);          // 2048 B
    int*      sum256 = (int*)(smem + 18432);          // 1024 B

    int tile0 = blockIdx.x * PT_TILE;
    int tid = threadIdx.x;

    for (int i = tid; i < nbuckets; i += 256) hist[i] = 0;
    __syncthreads();

    uint32 pck[PT_EPT];
    int    lofs[PT_EPT];
    short  bkt[PT_EPT];
#pragma unroll
    for (int j = 0; j < PT_EPT; ++j) {
        int e = tile0 + j * 256 + tid;
        if (e < E) {
            int s = load_idx(ei, e, i64);
            int d = load_idx(ei, E + e, i64);
            int b = d >> 8;
            pck[j]  = (uint32)s | ((uint32)(d & 255) << 24);
            bkt[j]  = (short)b;
            lofs[j] = atomicAdd(&hist[b], 1);
        } else bkt[j] = -1;
    }
    __syncthreads();

    for (int i = tid; i < nbuckets; i += 256)
        gbase[i] = hist[i] ? atomicAdd(&bcur[i], hist[i]) : 0;

    {   // exclusive scan of hist (2 elems/thread, MAXBK=512)
        int lt = tid * 2;
        int h0 = 0, h1 = 0;
        if (lt + 0 < nbuckets) h0 = hist[lt + 0];
        if (lt + 1 < nbuckets) h1 = hist[lt + 1];
        int lsum = h0 + h1;
        sum256[tid] = lsum;
        __syncthreads();
        for (int off = 1; off < 256; off <<= 1) {
            int t = (tid >= off) ? sum256[tid - off] : 0;
            __syncthreads();
            sum256[tid] += t;
            __syncthreads();
        }
        int excl = sum256[tid] - lsum;
        if (lt + 0 < nbuckets) scanb[lt + 0] = excl;
        if (lt + 1 < nbuckets) scanb[lt + 1] = excl + h0;
    }
    __syncthreads();

#pragma unroll
    for (int j = 0; j < PT_EPT; ++j) {
        if (bkt[j] >= 0) {
            int p = scanb[bkt[j]] + lofs[j];
            stash[p] = pck[j];
            bidx[p]  = (ushort16)bkt[j];
        }
    }
    __syncthreads();

    int total = min(PT_TILE, E - tile0);
    for (int k = tid; k < total; k += 256) {
        int b = bidx[k];
        int dst = gbase[b] + (k - scanb[b]);
        if (dst < bcap) bbuf[(size_t)b * bcap + dst] = stash[k];
    }
}

// ---------- mega1: blocks [0,PB) partition ; blocks [PB,..) raw layer-1 GEMM (LDS-staged) ----------
__global__ __launch_bounds__(256) void mega1_kernel(
    const void* __restrict__ ei, int E, const int* __restrict__ flag,
    int nbuckets, int bcap, int* __restrict__ bcur, uint32* __restrict__ bbuf,
    const float* __restrict__ X, const ushort16* __restrict__ W1t,
    ushort16* __restrict__ H, int M, int PB)
{
    __shared__ char smem[PART_SMEM];
    if ((int)blockIdx.x < PB) {
        partition_body(smem, ei, E, (*flag != 0), nbuckets, bcap, bcur, bbuf);
    } else {
        gemm_lds_body<HID, false, false>(smem, blockIdx.x - PB, X, W1t, nullptr, H, M);
    }
}

// ---------- bucket_build @1024 threads: bbase scan + degree/dis/row_ptr + CSR fill ----------
// R12 counters: 391 blocks x 256 thr = 1.5 blocks/CU (under-occupancy, same R7 disease).
// 1024 threads/block -> 16 waves/block, 24 waves/CU during hist+fill (the heavy phases).
__global__ __launch_bounds__(1024) void bucket_build_kernel(
    const uint32* __restrict__ bbuf, const int* __restrict__ bcur,
    int* __restrict__ counts, float* __restrict__ dis, int* __restrict__ row_ptr,
    int* __restrict__ csr, int N, int nbuckets, int bcap)
{
    __shared__ int pcnt[512];
    __shared__ int pinc[256];
    __shared__ int h[256];
    __shared__ int sc[256];
    __shared__ int cur[256];

    int tid = threadIdx.x;
    int b = blockIdx.x;

    if (tid < 512) pcnt[tid] = (tid < nbuckets) ? min(bcur[tid], bcap) : 0;
    if (tid < 256) h[tid] = 0;
    __syncthreads();
    if (tid < 256) pinc[tid] = pcnt[2 * tid] + pcnt[2 * tid + 1];
    __syncthreads();
    for (int off = 1; off < 256; off <<= 1) {
        int t = (tid >= off && tid < 256) ? pinc[tid - off] : 0;
        __syncthreads();
        if (tid < 256) pinc[tid] += t;
        __syncthreads();
    }
    int p2 = b >> 1;
    int bbase = pinc[p2] - (pcnt[2 * p2] + pcnt[2 * p2 + 1]) + ((b & 1) ? pcnt[b - 1] : 0);

    // degree histogram (1024 threads)
    int cnt = min(bcur[b], bcap);
    const uint32* src = bbuf + (size_t)b * bcap;
    for (int k = tid; k < cnt; k += 1024) atomicAdd(&h[src[k] >> 24], 1);
    __syncthreads();

    // local exclusive scan of per-node counts (first 256 threads)
    int v = (tid < 256) ? h[tid] : 0;
    if (tid < 256) sc[tid] = v;
    __syncthreads();
    for (int off = 1; off < 256; off <<= 1) {
        int t = (tid >= off && tid < 256) ? sc[tid - off] : 0;
        __syncthreads();
        if (tid < 256) sc[tid] += t;
        __syncthreads();
    }
    if (tid < 256) {
        int myrow = bbase + sc[tid] - v;
        int node = (b << 8) + tid;
        if (node < N) {
            counts[node]  = v;
            dis[node]     = rsqrtf((float)(v + 1));   // +1 self-loop
            row_ptr[node] = myrow;
        }
        cur[tid] = myrow;
    }
    __syncthreads();

    // CSR fill (1024 threads; bbuf chunk L2-hot from histogram pass)
    for (int k = tid; k < cnt; k += 1024) {
        uint32 p = src[k];
        int dl = p >> 24;
        int pos = atomicAdd(&cur[dl], 1);
        csr[pos] = (int)(p & 0xFFFFFF);
    }
}

// ---------- legacy build path (N too large for bucketed path) ----------
__global__ void hist_kernel(const void* __restrict__ ei, int E, const int* __restrict__ flag,
                            int* __restrict__ counts) {
    int e = blockIdx.x * TPB + threadIdx.x;
    if (e >= E) return;
    bool i64 = (*flag != 0);
    atomicAdd(&counts[load_idx(ei, E + e, i64)], 1);
}

__global__ void fill_kernel(const void* __restrict__ ei, int E, const int* __restrict__ flag,
                            int* __restrict__ cursor, int* __restrict__ csr_src) {
    int e = blockIdx.x * TPB + threadIdx.x;
    if (e >= E) return;
    bool i64 = (*flag != 0);
    int s = load_idx(ei, e, i64);
    int d = load_idx(ei, E + e, i64);
    int pos = atomicAdd(&cursor[d], 1);
    csr_src[pos] = s;
}

__global__ void dis_kernel(const int* __restrict__ counts, float* __restrict__ dis, int n) {
    int i = blockIdx.x * TPB + threadIdx.x;
    if (i < n) dis[i] = rsqrtf((float)(counts[i] + 1));
}

__global__ void scan_block_kernel(const int* __restrict__ counts, int* __restrict__ excl,
                                  int* __restrict__ partials, int n) {
    __shared__ int tmp[TPB];
    int tid = threadIdx.x, gid = blockIdx.x * TPB + tid;
    int v = (gid < n) ? counts[gid] : 0;
    tmp[tid] = v;
    __syncthreads();
    for (int off = 1; off < TPB; off <<= 1) {
        int t = (tid >= off) ? tmp[tid - off] : 0;
        __syncthreads();
        tmp[tid] += t;
        __syncthreads();
    }
    if (gid < n) excl[gid] = tmp[tid] - v;
    if (tid == TPB - 1) partials[blockIdx.x] = tmp[TPB - 1];
}

__global__ void scan_partials_kernel(int* __restrict__ partials, int nb) {
    __shared__ int tmp[512];
    int tid = threadIdx.x;
    int v = (tid < nb) ? partials[tid] : 0;
    tmp[tid] = v;
    __syncthreads();
    for (int off = 1; off < 512; off <<= 1) {
        int t = (tid >= off) ? tmp[tid - off] : 0;
        __syncthreads();
        tmp[tid] += t;
        __syncthreads();
    }
    if (tid < nb) partials[tid] = tmp[tid] - v;
}

__global__ void add_offsets_kernel(int* __restrict__ excl, const int* __restrict__ partials,
                                   int* __restrict__ cursor, int n) {
    int i = blockIdx.x * TPB + threadIdx.x;
    if (i < n) {
        int v = excl[i] + partials[blockIdx.x];
        excl[i] = v;
        cursor[i] = v;
    }
}

#define ACC8(u, d) \
    a0 = fmaf(d, bflo(u.x), a0); a1 = fmaf(d, bfhi(u.x), a1); \
    a2 = fmaf(d, bflo(u.y), a2); a3 = fmaf(d, bfhi(u.y), a3); \
    a4 = fmaf(d, bflo(u.z), a4); a5 = fmaf(d, bfhi(u.z), a5); \
    a6 = fmaf(d, bflo(u.w), a6); a7 = fmaf(d, bfhi(u.w), a7);

// ---------- aggregation C=128 (raw h in, dis[s] folded in gather) ----------
__global__ __launch_bounds__(256) void agg128_kernel(
    const uint32* __restrict__ hs, const int* __restrict__ csr,
    const int* __restrict__ row_ptr, const int* __restrict__ counts,
    const float* __restrict__ dis, const float* __restrict__ b,
    uint32* __restrict__ out, int n)
{
    int wave = threadIdx.x >> 6;
    int lane = threadIdx.x & 63;
    int g    = lane >> 4;        // quarter 0..3
    int sl   = lane & 15;
    int node = blockIdx.x * 4 + wave;
    if (node >= n) return;

    const uint4* hsv = (const uint4*)hs;   // row = 16 uint4 (128 bf16)
    float dsc = dis[node];
    float a0 = 0.f, a1 = 0.f, a2 = 0.f, a3 = 0.f,
          a4 = 0.f, a5 = 0.f, a6 = 0.f, a7 = 0.f;
    if (g == 0) {   // self-loop: dis[d]*h[d]
        uint4 u = hsv[(size_t)node * 16 + sl];
        ACC8(u, dsc);
    }

    int start = row_ptr[node];
    int end   = start + counts[node];
    int k = start;
    for (; k + 15 < end; k += 16) {
        int base = k + (g << 2);
        int s0 = csr[base], s1 = csr[base + 1], s2 = csr[base + 2], s3 = csr[base + 3];
        float d0 = dis[s0], d1 = dis[s1], d2 = dis[s2], d3 = dis[s3];
        uint4 u0 = hsv[(size_t)s0 * 16 + sl];
        uint4 u1 = hsv[(size_t)s1 * 16 + sl];
        uint4 u2 = hsv[(size_t)s2 * 16 + sl];
        uint4 u3 = hsv[(size_t)s3 * 16 + sl];
        ACC8(u0, d0); ACC8(u1, d1); ACC8(u2, d2); ACC8(u3, d3);
    }
    for (; k + 7 < end; k += 8) {
        int base = k + (g << 1);
        int s0 = csr[base], s1 = csr[base + 1];
        float d0 = dis[s0], d1 = dis[s1];
        uint4 u0 = hsv[(size_t)s0 * 16 + sl];
        uint4 u1 = hsv[(size_t)s1 * 16 + sl];
        ACC8(u0, d0); ACC8(u1, d1);
    }
    for (; k < end; k += 4) {
        int e = k + g;
        if (e < end) {
            int s0 = csr[e];
            float d0 = dis[s0];
            uint4 u = hsv[(size_t)s0 * 16 + sl];
            ACC8(u, d0);
        }
    }

    a0 += __shfl_xor(a0, 16, 64); a0 += __shfl_xor(a0, 32, 64);
    a1 += __shfl_xor(a1, 16, 64); a1 += __shfl_xor(a1, 32, 64);
    a2 += __shfl_xor(a2, 16, 64); a2 += __shfl_xor(a2, 32, 64);
    a3 += __shfl_xor(a3, 16, 64); a3 += __shfl_xor(a3, 32, 64);
    a4 += __shfl_xor(a4, 16, 64); a4 += __shfl_xor(a4, 32, 64);
    a5 += __shfl_xor(a5, 16, 64); a5 += __shfl_xor(a5, 32, 64);
    a6 += __shfl_xor(a6, 16, 64); a6 += __shfl_xor(a6, 32, 64);
    a7 += __shfl_xor(a7, 16, 64); a7 += __shfl_xor(a7, 32, 64);

    if (g == 0) {
        float4 bb0 = ((const float4*)b)[sl * 2];
        float4 bb1 = ((const float4*)b)[sl * 2 + 1];
        float v0 = fmaxf(a0 * dsc + bb0.x, 0.0f);
        float v1 = fmaxf(a1 * dsc + bb0.y, 0.0f);
        float v2 = fmaxf(a2 * dsc + bb0.z, 0.0f);
        float v3 = fmaxf(a3 * dsc + bb0.w, 0.0f);
        float v4 = fmaxf(a4 * dsc + bb1.x, 0.0f);
        float v5 = fmaxf(a5 * dsc + bb1.y, 0.0f);
        float v6 = fmaxf(a6 * dsc + bb1.z, 0.0f);
        float v7 = fmaxf(a7 * dsc + bb1.w, 0.0f);
        uint4 o;
        o.x = packbf(v0, v1); o.y = packbf(v2, v3);
        o.z = packbf(v4, v5); o.w = packbf(v6, v7);
        ((uint4*)out)[(size_t)node * 16 + sl] = o;
    }
}

// ---------- aggregation C=64 (hs2 has dis folded), eighth-wave per edge ----------
__global__ __launch_bounds__(256) void agg64_kernel(
    const uint32* __restrict__ hs, const int* __restrict__ csr,
    const int* __restrict__ row_ptr, const int* __restrict__ counts,
    const float* __restrict__ dis, const float* __restrict__ b,
    float* __restrict__ out, int n)
{
    int wave = threadIdx.x >> 6;
    int lane = threadIdx.x & 63;
    int g    = lane >> 3;        // eighth 0..7
    int sl   = lane & 7;
    int node = blockIdx.x * 4 + wave;
    if (node >= n) return;

    const uint4* hsv = (const uint4*)hs;   // row = 8 uint4 (64 bf16)
    float a0 = 0.f, a1 = 0.f, a2 = 0.f, a3 = 0.f,
          a4 = 0.f, a5 = 0.f, a6 = 0.f, a7 = 0.f;
    if (g == 0) {
        uint4 u = hsv[(size_t)node * 8 + sl];
        ACC8(u, 1.0f);
    }

    int start = row_ptr[node];
    int end   = start + counts[node];
    int k = start;
    for (; k + 15 < end; k += 16) {
        int base = k + (g << 1);
        int s0 = csr[base], s1 = csr[base + 1];
        uint4 u0 = hsv[(size_t)s0 * 8 + sl];
        uint4 u1 = hsv[(size_t)s1 * 8 + sl];
        ACC8(u0, 1.0f); ACC8(u1, 1.0f);
    }
    for (; k + 7 < end; k += 8) {
        int e = k + g;
        uint4 u = hsv[(size_t)csr[e] * 8 + sl];
        ACC8(u, 1.0f);
    }
    for (; k < end; k += 8) {
        int e = k + g;
        if (e < end) {
            uint4 u = hsv[(size_t)csr[e] * 8 + sl];
            ACC8(u, 1.0f);
        }
    }

    a0 += __shfl_xor(a0, 8, 64); a0 += __shfl_xor(a0, 16, 64); a0 += __shfl_xor(a0, 32, 64);
    a1 += __shfl_xor(a1, 8, 64); a1 += __shfl_xor(a1, 16, 64); a1 += __shfl_xor(a1, 32, 64);
    a2 += __shfl_xor(a2, 8, 64); a2 += __shfl_xor(a2, 16, 64); a2 += __shfl_xor(a2, 32, 64);
    a3 += __shfl_xor(a3, 8, 64); a3 += __shfl_xor(a3, 16, 64); a3 += __shfl_xor(a3, 32, 64);
    a4 += __shfl_xor(a4, 8, 64); a4 += __shfl_xor(a4, 16, 64); a4 += __shfl_xor(a4, 32, 64);
    a5 += __shfl_xor(a5, 8, 64); a5 += __shfl_xor(a5, 16, 64); a5 += __shfl_xor(a5, 32, 64);
    a6 += __shfl_xor(a6, 8, 64); a6 += __shfl_xor(a6, 16, 64); a6 += __shfl_xor(a6, 32, 64);
    a7 += __shfl_xor(a7, 8, 64); a7 += __shfl_xor(a7, 16, 64); a7 += __shfl_xor(a7, 32, 64);

    if (g == 0) {
        float dsc = dis[node];
        float4 bb0 = ((const float4*)b)[sl * 2];
        float4 bb1 = ((const float4*)b)[sl * 2 + 1];
        float4 o0, o1;
        o0.x = 0.1f + 0.8f / (1.0f + __expf(-(a0 * dsc + bb0.x)));
        o0.y = 0.1f + 0.8f / (1.0f + __expf(-(a1 * dsc + bb0.y)));
        o0.z = 0.1f + 0.8f / (1.0f + __expf(-(a2 * dsc + bb0.z)));
        o0.w = 0.1f + 0.8f / (1.0f + __expf(-(a3 * dsc + bb0.w)));
        o1.x = 0.1f + 0.8f / (1.0f + __expf(-(a4 * dsc + bb1.x)));
        o1.y = 0.1f + 0.8f / (1.0f + __expf(-(a5 * dsc + bb1.y)));
        o1.z = 0.1f + 0.8f / (1.0f + __expf(-(a6 * dsc + bb1.z)));
        o1.w = 0.1f + 0.8f / (1.0f + __expf(-(a7 * dsc + bb1.w)));
        ((float4*)out)[(size_t)node * 16 + sl * 2]     = o0;
        ((float4*)out)[(size_t)node * 16 + sl * 2 + 1] = o1;
    }
}

extern "C" void kernel_launch(void* const* d_in, const int* in_sizes, int n_in,
                              void* d_out, int out_size, void* d_ws, size_t ws_size,
                              hipStream_t stream) {
    const float* x  = (const float*)d_in[0];
    const void*  ei = d_in[1];
    const float* W1 = (const float*)d_in[2];
    const float* b1 = (const float*)d_in[3];
    const float* W2 = (const float*)d_in[4];
    const float* b2 = (const float*)d_in[5];

    const int N = in_sizes[0] / IN_F;   // 100000
    const int E = in_sizes[1] / 2;      // 1600000

    const int nbuckets = (N + 255) >> 8;                 // 391
    const int bcap     = (int)(2 * ((long long)E / (nbuckets > 0 ? nbuckets : 1)) + 2048);
    const bool bucketed = (nbuckets <= MAXBK);

    auto alignup = [](size_t v) { return (v + 255) & ~(size_t)255; };
    char* w = (char*)d_ws;
    size_t off = 0;
    int*      flag     = (int*)(w + off);      off = alignup(off + 16);
    int*      counts   = (int*)(w + off);      off = alignup(off + (size_t)(N + MAXBK) * sizeof(int));
    int*      bcur     = counts + N;           // contiguous with counts (R2 lesson)
    ushort16* W1t      = (ushort16*)(w + off); off = alignup(off + 128 * 128 * sizeof(ushort16));
    ushort16* W2t      = (ushort16*)(w + off); off = alignup(off + 64 * 128 * sizeof(ushort16));
    int*      cursor   = (int*)(w + off);      off = alignup(off + (size_t)N * sizeof(int));
    int*      row_ptr  = (int*)(w + off);      off = alignup(off + (size_t)N * sizeof(int));
    int*      partials = (int*)(w + off);      off = alignup(off + 512 * sizeof(int));
    float*    dis      = (float*)(w + off);    off = alignup(off + (size_t)N * sizeof(float));
    int*      csr      = (int*)(w + off);      off = alignup(off + (size_t)E * sizeof(int));
    uint32*   bbuf     = (uint32*)(w + off);   off = alignup(off + (size_t)nbuckets * bcap * sizeof(uint32));
    uint32*   A        = (uint32*)(w + off);   off = alignup(off + (size_t)N * HID * sizeof(ushort16));
    uint32*   B        = (uint32*)(w + off);   off = alignup(off + (size_t)N * HID * sizeof(ushort16));

    const int nbN = (N + TPB - 1) / TPB;   // 391
    const int nbE = (E + TPB - 1) / TPB;
    const int gemmBlocks = (N + 63) / 64;  // 1563
    const int prepBlocks = 1 + (128 * 128 + 128 * 64 + TPB - 1) / TPB;

    prep_kernel<<<prepBlocks, TPB, 0, stream>>>((const uint32*)ei, flag, bcur, W1, W2, W1t, W2t);

    if (bucketed) {
        const int PB = (E + PT_TILE - 1) / PT_TILE;     // 782 partition blocks
        mega1_kernel<<<PB + gemmBlocks, TPB, 0, stream>>>(
            ei, E, flag, nbuckets, bcap, bcur, bbuf, x, W1t, (ushort16*)A, N, PB);
        bucket_build_kernel<<<nbuckets, 1024, 0, stream>>>(
            bbuf, bcur, counts, dis, row_ptr, csr, N, nbuckets, bcap);
    } else {
        hipMemsetAsync(counts, 0, (size_t)(N + MAXBK) * sizeof(int), stream);
        hist_kernel<<<nbE, TPB, 0, stream>>>(ei, E, flag, counts);
        dis_kernel<<<nbN, TPB, 0, stream>>>(counts, dis, N);
        scan_block_kernel<<<nbN, TPB, 0, stream>>>(counts, row_ptr, partials, N);
        scan_partials_kernel<<<1, 512, 0, stream>>>(partials, nbN);
        add_offsets_kernel<<<nbN, TPB, 0, stream>>>(row_ptr, partials, cursor, N);
        fill_kernel<<<nbE, TPB, 0, stream>>>(ei, E, flag, cursor, csr);
        gemm_lds_kernel<HID, false, false><<<gemmBlocks, TPB, 0, stream>>>(x, W1t, dis, (ushort16*)A, N);
    }

    // ---- layer 1 aggregation: h1 = relu(dis*(dis*h[d] + sum dis[s]h[s]) + b1)
    agg128_kernel<<<(N + 3) / 4, TPB, 0, stream>>>(A, csr, row_ptr, counts, dis, b1, B, N);

    // ---- layer 2: hs2 = bf16((h1@W2)*dis) ; out = 0.1+0.8*sigmoid(dis*(hs2[d]+sum hs2[s])+b2)
    gemm_lds_kernel<OUTF, true, true><<<gemmBlocks, TPB, 0, stream>>>(B, W2t, dis, (ushort16*)A, N);
    agg64_kernel<<<(N + 3) / 4, TPB, 0, stream>>>(A, csr, row_ptr, counts, dis, b2, (float*)d_out, N);
}